// Round 14
// baseline (170.735 us; speedup 1.0000x reference)
//
#include <hip/hip_runtime.h>

#define THREADS 256
#define SEG 2048
#define CONV_BLOCKS 2048
#define AT_LD 68
#define BN_EPS 1e-5f

// ---------------- init (1 block): bucket cursors to region bases, zero stats ---------
__global__ __launch_bounds__(THREADS) void init_kernel(int* __restrict__ bcursor, int cap,
                                                       float* __restrict__ stats) {
    int t = threadIdx.x;
    bcursor[t] = t * cap;
    if (t < 128) stats[t] = 0.f;
}

// ---------------- fused: partition (blocks 0..nPart) ∥ x->bf16 convert ----------------
// staging = src | dstlow<<16 (valid while N <= 65536); per-bucket fixed-capacity
// regions [b*cap, (b+1)*cap) -- no histogram/scan needed (cap has ~8-sigma slack).
__global__ __launch_bounds__(THREADS) void conv_part_kernel(const int* __restrict__ src,
                                                            const int* __restrict__ dst, int E,
                                                            int nPart,
                                                            int* __restrict__ bcursor,
                                                            unsigned* __restrict__ staging,
                                                            const float4* __restrict__ x4,
                                                            ushort* __restrict__ xh, int n4) {
    int bid = blockIdx.x;
    int tid = threadIdx.x;
    if (bid < nPart) {
        __shared__ int hist[256];
        __shared__ int gbase[256];
        __shared__ int lcnt[256];
        int nseg = (E + SEG - 1) / SEG;
        for (int seg = bid; seg < nseg; seg += nPart) {
            int base = seg * SEG;
            int lim = min(E, base + SEG);
            hist[tid] = 0;
            __syncthreads();
            for (int i = base + tid; i < lim; i += THREADS)
                atomicAdd(&hist[dst[i] >> 8], 1);
            __syncthreads();
            if (hist[tid] > 0) gbase[tid] = atomicAdd(&bcursor[tid], hist[tid]);
            lcnt[tid] = 0;
            __syncthreads();
            for (int i = base + tid; i < lim; i += THREADS) {
                int d = dst[i];
                int b = d >> 8;
                int p = gbase[b] + atomicAdd(&lcnt[b], 1);
                staging[p] = (unsigned)src[i] | ((unsigned)(d & 255) << 16);
            }
            __syncthreads();
        }
    } else {
        int cb = bid - nPart;
        for (int t = cb * THREADS + tid; t < n4; t += CONV_BLOCKS * THREADS) {
            float4 v = x4[t];
            const float* f = (const float*)&v;
            ushort u[4];
#pragma unroll
            for (int k = 0; k < 4; ++k) {
                unsigned b = __float_as_uint(f[k]);
                u[k] = (ushort)((b + 0x7FFFu + ((b >> 16) & 1u)) >> 16);  // RNE
            }
            *(ushort4*)(&xh[t * 4]) = make_ushort4(u[0], u[1], u[2], u[3]);
        }
    }
}

// ---------------- per-bucket build: deg/offs/dinv + CSR fill, all LDS atomics --------
__global__ __launch_bounds__(THREADS) void bucket_build_kernel(const unsigned* __restrict__ staging,
                                                               const int* __restrict__ bcursor,
                                                               int cap, int N,
                                                               int* __restrict__ deg,
                                                               int* __restrict__ offs,
                                                               float* __restrict__ dinv,
                                                               int* __restrict__ csr) {
    __shared__ int hist[256];
    __shared__ int lofs[256];
    __shared__ int lcur[256];
    int tid = threadIdx.x;
    int b = blockIdx.x;
    int s = b * cap;
    int e = bcursor[b];  // final cursor = s + count(bucket b)

    hist[tid] = 0;
    __syncthreads();
    for (int i = s + tid; i < e; i += THREADS)
        atomicAdd(&hist[staging[i] >> 16], 1);
    __syncthreads();

    int v = hist[tid];
    lofs[tid] = v;
    __syncthreads();
    for (int off = 1; off < 256; off <<= 1) {
        int u = (tid >= off) ? lofs[tid - off] : 0;
        __syncthreads();
        lofs[tid] += u;
        __syncthreads();
    }
    int excl = lofs[tid] - v;

    int node = (b << 8) + tid;
    if (node < N) {
        deg[node] = v;
        offs[node] = s + excl;
        dinv[node] = rsqrtf((float)v + 1.0f);  // +1 self-loop
    }
    lcur[tid] = excl;
    __syncthreads();

    for (int i = s + tid; i < e; i += THREADS) {
        unsigned w = staging[i];
        int ln = (int)(w >> 16);
        int p = atomicAdd(&lcur[ln], 1);
        csr[s + p] = (int)(w & 0xFFFFu);
    }
}

// ---------------- pull aggregation, FEATURE-SPLIT: 32 features per pass --------------
// Per pass the hot gather array is a 4.2MB half of xh -> fits the 4MiB per-XCD L2.
// Lanes 32-63 duplicate lanes 0-31 (same 64B segment, broadcast); only lane<32 writes.
__device__ __forceinline__ float bf2f(ushort u) {
    return __uint_as_float(((unsigned)u) << 16);
}

__global__ __launch_bounds__(THREADS) void gather_half_kernel(const ushort* __restrict__ xh,
                                                              const int* __restrict__ offs,
                                                              const int* __restrict__ deg,
                                                              const int* __restrict__ csr,
                                                              const float* __restrict__ dinv,
                                                              float* __restrict__ out, int N,
                                                              int half) {
    int lane = threadIdx.x & 63;
    int node = __builtin_amdgcn_readfirstlane(
        (int)((blockIdx.x * blockDim.x + threadIdx.x) >> 6));
    if (node >= N) return;
    int feat = (half << 5) + (lane & 31);
    float dd = dinv[node];
    float acc = dd * bf2f(xh[((size_t)node << 6) + feat]);  // self-loop
    int start = offs[node];
    int cnt = deg[node];
    const int* __restrict__ row = csr + start;
    int j = 0;
    for (; j + 16 <= cnt; j += 16) {
        int s[16];
        float w[16];
        ushort u[16];
#pragma unroll
        for (int q = 0; q < 16; ++q) s[q] = __builtin_amdgcn_readfirstlane(row[j + q]);
#pragma unroll
        for (int q = 0; q < 16; ++q) w[q] = dinv[s[q]];
#pragma unroll
        for (int q = 0; q < 16; ++q) u[q] = xh[((size_t)s[q] << 6) + feat];
#pragma unroll
        for (int q = 0; q < 16; ++q) acc += w[q] * bf2f(u[q]);
    }
    for (; j + 4 <= cnt; j += 4) {
        int s[4];
        float w[4];
        ushort u[4];
#pragma unroll
        for (int q = 0; q < 4; ++q) s[q] = __builtin_amdgcn_readfirstlane(row[j + q]);
#pragma unroll
        for (int q = 0; q < 4; ++q) w[q] = dinv[s[q]];
#pragma unroll
        for (int q = 0; q < 4; ++q) u[q] = xh[((size_t)s[q] << 6) + feat];
#pragma unroll
        for (int q = 0; q < 4; ++q) acc += w[q] * bf2f(u[q]);
    }
    for (; j < cnt; ++j) {
        int s = __builtin_amdgcn_readfirstlane(row[j]);
        acc += dinv[s] * bf2f(xh[((size_t)s << 6) + feat]);
    }
    if (lane < 32) out[((size_t)node << 6) + feat] = dd * acc;
}

// ---------------- LDS-tiled in-place matmul io = io @ W, fused stats ----------------
// W read from GLOBAL (16KB, L1-resident broadcast) -- halves LDS-pipe traffic and
// LDS/block (18KB -> 8 blocks/CU). k-loop rolled (full unroll spilled, R4).
__global__ __launch_bounds__(THREADS) void matmul_stats_kernel(float* __restrict__ io,
                                                               const float* __restrict__ W,
                                                               float* __restrict__ stats, int N) {
    __shared__ float At[64 * AT_LD];
    __shared__ float bred[128];
    int tid = threadIdx.x;
    const float4* W4 = (const float4*)W;

    int c4 = tid & 15;          // float4-column index; c0 = 4*c4
    int c0 = c4 << 2;
    int r0 = (tid >> 4) * 4;
    int ntiles = (N + 63) >> 6;
    float sums[4] = {0.f, 0.f, 0.f, 0.f};
    float sqs[4] = {0.f, 0.f, 0.f, 0.f};

    if (tid < 128) bred[tid] = 0.f;

    for (int tile = blockIdx.x; tile < ntiles; tile += gridDim.x) {
        int base = tile << 6;
        __syncthreads();  // At reads of prev iter done
        for (int g = tid; g < 1024; g += THREADS) {
            int r = g >> 4, cc = (g & 15) << 2;
            int rowi = base + r;
            float4 v = {0.f, 0.f, 0.f, 0.f};
            if (rowi < N) v = *(const float4*)(io + ((size_t)rowi << 6) + cc);
            *(float4*)(&At[r * AT_LD + cc]) = v;
        }
        __syncthreads();

        float acc[4][4] = {};
#pragma unroll 1
        for (int k0 = 0; k0 < 64; k0 += 4) {
            float4 a[4], wf[4];
#pragma unroll
            for (int i = 0; i < 4; ++i)
                a[i] = *(const float4*)(&At[(r0 + i) * AT_LD + k0]);
#pragma unroll
            for (int q = 0; q < 4; ++q)
                wf[q] = W4[((k0 + q) << 4) + c4];  // L1 broadcast
#pragma unroll
            for (int i = 0; i < 4; ++i) {
                const float* ap = (const float*)&a[i];
#pragma unroll
                for (int j = 0; j < 4; ++j) {
                    acc[i][j] += ap[0] * ((const float*)&wf[0])[j] +
                                 ap[1] * ((const float*)&wf[1])[j] +
                                 ap[2] * ((const float*)&wf[2])[j] +
                                 ap[3] * ((const float*)&wf[3])[j];
                }
            }
        }

#pragma unroll
        for (int i = 0; i < 4; ++i) {
            int rowi = base + r0 + i;
            if (rowi < N) {
                float4 o = {acc[i][0], acc[i][1], acc[i][2], acc[i][3]};
                *(float4*)(io + ((size_t)rowi << 6) + c0) = o;
#pragma unroll
                for (int j = 0; j < 4; ++j) {
                    sums[j] += acc[i][j];
                    sqs[j] += acc[i][j] * acc[i][j];
                }
            }
        }
    }

    __syncthreads();
#pragma unroll
    for (int j = 0; j < 4; ++j) {
        atomicAdd(&bred[c0 + j], sums[j]);
        atomicAdd(&bred[64 + c0 + j], sqs[j]);
    }
    __syncthreads();
    if (tid < 128) atomicAdd(&stats[tid], bred[tid]);
}

// ---------------- BN + ReLU in place ----------------
__global__ __launch_bounds__(THREADS) void bn_relu_kernel(float* __restrict__ io,
                                                          const float* __restrict__ stats,
                                                          const float* __restrict__ gamma,
                                                          const float* __restrict__ beta,
                                                          int n4, float invN) {
    int t = blockIdx.x * blockDim.x + threadIdx.x;
    if (t >= n4) return;
    int f0 = (t & 15) * 4;
    float4 v = ((const float4*)io)[t];
    float vv[4] = {v.x, v.y, v.z, v.w};
    float o[4];
#pragma unroll
    for (int j = 0; j < 4; ++j) {
        int f = f0 + j;
        float mean = stats[f] * invN;
        float var = stats[64 + f] * invN - mean * mean;
        float scale = gamma[f] * rsqrtf(var + BN_EPS);
        float shift = beta[f] - mean * scale;
        float y = vv[j] * scale + shift;
        o[j] = y > 0.f ? y : 0.f;
    }
    float4 r = {o[0], o[1], o[2], o[3]};
    ((float4*)io)[t] = r;
}

// ================= fallback (push path) kernels =================
__global__ __launch_bounds__(THREADS) void deg_kernel(const int* __restrict__ dst, int E,
                                                      int* __restrict__ deg) {
    int e = blockIdx.x * blockDim.x + threadIdx.x;
    if (e < E) atomicAdd(&deg[dst[e]], 1);
}

__global__ __launch_bounds__(THREADS) void dinv_kernel(const int* __restrict__ deg,
                                                       float* __restrict__ dinv, int N) {
    int i = blockIdx.x * blockDim.x + threadIdx.x;
    if (i < N) dinv[i] = rsqrtf((float)deg[i] + 1.0f);
}

__global__ __launch_bounds__(THREADS) void selfloop_kernel(const float4* __restrict__ x4,
                                                           const float* __restrict__ dinv,
                                                           float4* __restrict__ out4, int n4) {
    int t = blockIdx.x * blockDim.x + threadIdx.x;
    if (t >= n4) return;
    int node = t >> 4;
    float s = dinv[node];
    s *= s;
    float4 v = x4[t];
    v.x *= s; v.y *= s; v.z *= s; v.w *= s;
    out4[t] = v;
}

__global__ __launch_bounds__(THREADS) void scatter_kernel(const int* __restrict__ src,
                                                          const int* __restrict__ dst, int E,
                                                          const float* __restrict__ x,
                                                          const float* __restrict__ dinv,
                                                          float* __restrict__ out) {
    int lane = threadIdx.x & 63;
    int wave = (blockIdx.x * blockDim.x + threadIdx.x) >> 6;
    int nwaves = (gridDim.x * blockDim.x) >> 6;
    for (int e = wave; e < E; e += nwaves) {
        int s = src[e];
        int d = dst[e];
        float nrm = dinv[s] * dinv[d];
        atomicAdd(&out[d * 64 + lane], x[s * 64 + lane] * nrm);
    }
}

extern "C" void kernel_launch(void* const* d_in, const int* in_sizes, int n_in,
                              void* d_out, int out_size, void* d_ws, size_t ws_size,
                              hipStream_t stream) {
    const float* x     = (const float*)d_in[0];
    const int*   edges = (const int*)d_in[1];
    const float* W     = (const float*)d_in[2];
    // d_in[3] = b cancels exactly in training-mode BN
    const float* gamma = (const float*)d_in[4];
    const float* beta  = (const float*)d_in[5];
    float* out = (float*)d_out;

    const int N = in_sizes[0] / 64;
    const int E = in_sizes[1] / 2;
    const int* src = edges;
    const int* dst = edges + E;
    const int n4 = N * 16;

    const int nb = (N + 255) >> 8;                     // buckets
    const int avg = (E + nb - 1) / nb;
    const int cap = avg + (avg >> 2) + 512;            // ~8-sigma slack for Binomial load

    char* ws = (char*)d_ws;
    // layout: stats f32[128] | bcursor[256] | deg[N] | offs[N] | dinv[N] |
    //         csr[nb*cap] | staging[nb*cap] | xh[64N ushort]
    size_t off_stats   = 0;
    size_t off_bcursor = 512;
    size_t off_deg     = off_bcursor + 1024;
    size_t off_offs    = off_deg + (size_t)4 * N;
    size_t off_dinv    = off_offs + (size_t)4 * N;
    size_t off_csr     = off_dinv + (size_t)4 * N;
    size_t off_staging = off_csr + (size_t)4 * nb * cap;
    size_t off_xh      = (off_staging + (size_t)4 * nb * cap + 15) & ~(size_t)15;
    size_t need        = off_xh + (size_t)128 * N;

    if (ws_size >= need && N <= 65536) {
        float* stats   = (float*)(ws + off_stats);
        int*   bcursor = (int*)(ws + off_bcursor);
        int*   deg     = (int*)(ws + off_deg);
        int*   offs    = (int*)(ws + off_offs);
        float* dinv    = (float*)(ws + off_dinv);
        int*   csr     = (int*)(ws + off_csr);
        unsigned* staging = (unsigned*)(ws + off_staging);
        ushort* xh     = (ushort*)(ws + off_xh);

        int nseg = (E + SEG - 1) / SEG;
        int nPart = nseg < 1024 ? nseg : 1024;
        int gblocks = (N * 64 + THREADS - 1) / THREADS;

        init_kernel<<<1, THREADS, 0, stream>>>(bcursor, cap, stats);
        conv_part_kernel<<<nPart + CONV_BLOCKS, THREADS, 0, stream>>>(
            src, dst, E, nPart, bcursor, staging, (const float4*)x, xh, n4);
        bucket_build_kernel<<<nb, THREADS, 0, stream>>>(staging, bcursor, cap, N, deg, offs,
                                                        dinv, csr);
        gather_half_kernel<<<gblocks, THREADS, 0, stream>>>(xh, offs, deg, csr, dinv, out, N,
                                                            0);
        gather_half_kernel<<<gblocks, THREADS, 0, stream>>>(xh, offs, deg, csr, dinv, out, N,
                                                            1);
        int ntiles = (N + 63) >> 6;
        matmul_stats_kernel<<<(ntiles < 1024 ? ntiles : 1024), THREADS, 0, stream>>>(
            out, W, stats, N);
        bn_relu_kernel<<<(n4 + THREADS - 1) / THREADS, THREADS, 0, stream>>>(
            out, stats, gamma, beta, n4, 1.0f / (float)N);
    } else {
        // fallback: push path (ws: deg[N] | stats[128] | dinv[N])
        int*   deg   = (int*)ws;
        float* stats = (float*)(ws + (size_t)N * 4);
        float* dinv  = (float*)(ws + (size_t)N * 4 + 512);

        hipMemsetAsync(ws, 0, (size_t)N * 4 + 512, stream);
        deg_kernel<<<(E + THREADS - 1) / THREADS, THREADS, 0, stream>>>(dst, E, deg);
        dinv_kernel<<<(N + THREADS - 1) / THREADS, THREADS, 0, stream>>>(deg, dinv, N);
        selfloop_kernel<<<(n4 + THREADS - 1) / THREADS, THREADS, 0, stream>>>(
            (const float4*)x, dinv, (float4*)out, n4);
        scatter_kernel<<<1024, THREADS, 0, stream>>>(src, dst, E, x, dinv, out);
        // push-path matmul fallback: reuse matmul_stats_kernel
        matmul_stats_kernel<<<512, THREADS, 0, stream>>>(out, W, stats, N);
        bn_relu_kernel<<<(n4 + THREADS - 1) / THREADS, THREADS, 0, stream>>>(
            out, stats, gamma, beta, n4, 1.0f / (float)N);
    }
}

// Round 15
// 129.973 us; speedup vs baseline: 1.3136x; 1.3136x over previous
//
#include <hip/hip_runtime.h>

#define THREADS 256
#define SEG 4096
#define CONV_BLOCKS 2048
#define AT_LD 68
#define BN_EPS 1e-5f

// ---------------- init (1 block): bucket cursors to region bases, zero stats ---------
__global__ __launch_bounds__(THREADS) void init_kernel(int* __restrict__ bcursor, int cap,
                                                       float* __restrict__ stats) {
    int t = threadIdx.x;
    bcursor[t] = t * cap;
    if (t < 128) stats[t] = 0.f;
}

// ---------------- fused: partition (blocks 0..nPart) ∥ x->bf16 convert ----------------
// staging = src | dstlow<<16 (valid while N <= 65536); per-bucket fixed-capacity
// regions [b*cap, (b+1)*cap) -- no histogram/scan needed (cap has ~8-sigma slack).
__global__ __launch_bounds__(THREADS) void conv_part_kernel(const int* __restrict__ src,
                                                            const int* __restrict__ dst, int E,
                                                            int nPart,
                                                            int* __restrict__ bcursor,
                                                            unsigned* __restrict__ staging,
                                                            const float4* __restrict__ x4,
                                                            ushort* __restrict__ xh, int n4) {
    int bid = blockIdx.x;
    int tid = threadIdx.x;
    if (bid < nPart) {
        __shared__ int hist[256];
        __shared__ int gbase[256];
        __shared__ int lcnt[256];
        int nseg = (E + SEG - 1) / SEG;
        for (int seg = bid; seg < nseg; seg += nPart) {
            int base = seg * SEG;
            int lim = min(E, base + SEG);
            hist[tid] = 0;
            __syncthreads();
            for (int i = base + tid; i < lim; i += THREADS)
                atomicAdd(&hist[dst[i] >> 8], 1);
            __syncthreads();
            if (hist[tid] > 0) gbase[tid] = atomicAdd(&bcursor[tid], hist[tid]);
            lcnt[tid] = 0;
            __syncthreads();
            for (int i = base + tid; i < lim; i += THREADS) {
                int d = dst[i];
                int b = d >> 8;
                int p = gbase[b] + atomicAdd(&lcnt[b], 1);
                staging[p] = (unsigned)src[i] | ((unsigned)(d & 255) << 16);
            }
            __syncthreads();
        }
    } else {
        int cb = bid - nPart;
        for (int t = cb * THREADS + tid; t < n4; t += CONV_BLOCKS * THREADS) {
            float4 v = x4[t];
            const float* f = (const float*)&v;
            ushort u[4];
#pragma unroll
            for (int k = 0; k < 4; ++k) {
                unsigned b = __float_as_uint(f[k]);
                u[k] = (ushort)((b + 0x7FFFu + ((b >> 16) & 1u)) >> 16);  // RNE
            }
            *(ushort4*)(&xh[t * 4]) = make_ushort4(u[0], u[1], u[2], u[3]);
        }
    }
}

// ---------------- per-bucket build: deg/offs/dinv + CSR fill, all LDS atomics --------
__global__ __launch_bounds__(THREADS) void bucket_build_kernel(const unsigned* __restrict__ staging,
                                                               const int* __restrict__ bcursor,
                                                               int cap, int N,
                                                               int* __restrict__ deg,
                                                               int* __restrict__ offs,
                                                               float* __restrict__ dinv,
                                                               int* __restrict__ csr) {
    __shared__ int hist[256];
    __shared__ int lofs[256];
    __shared__ int lcur[256];
    int tid = threadIdx.x;
    int b = blockIdx.x;
    int s = b * cap;
    int e = bcursor[b];  // final cursor = s + count(bucket b)

    hist[tid] = 0;
    __syncthreads();
    for (int i = s + tid; i < e; i += THREADS)
        atomicAdd(&hist[staging[i] >> 16], 1);
    __syncthreads();

    int v = hist[tid];
    lofs[tid] = v;
    __syncthreads();
    for (int off = 1; off < 256; off <<= 1) {
        int u = (tid >= off) ? lofs[tid - off] : 0;
        __syncthreads();
        lofs[tid] += u;
        __syncthreads();
    }
    int excl = lofs[tid] - v;

    int node = (b << 8) + tid;
    if (node < N) {
        deg[node] = v;
        offs[node] = s + excl;
        dinv[node] = rsqrtf((float)v + 1.0f);  // +1 self-loop
    }
    lcur[tid] = excl;
    __syncthreads();

    for (int i = s + tid; i < e; i += THREADS) {
        unsigned w = staging[i];
        int ln = (int)(w >> 16);
        int p = atomicAdd(&lcur[ln], 1);
        csr[s + p] = (int)(w & 0xFFFFu);
    }
}

// ---------------- pull aggregation from bf16 x: wave/node, 16-deep MLP ----------------
__device__ __forceinline__ float bf2f(ushort u) {
    return __uint_as_float(((unsigned)u) << 16);
}

__global__ __launch_bounds__(THREADS) void gather_bf16_kernel(const ushort* __restrict__ xh,
                                                              const int* __restrict__ offs,
                                                              const int* __restrict__ deg,
                                                              const int* __restrict__ csr,
                                                              const float* __restrict__ dinv,
                                                              float* __restrict__ out, int N) {
    int lane = threadIdx.x & 63;
    int node = __builtin_amdgcn_readfirstlane(
        (int)((blockIdx.x * blockDim.x + threadIdx.x) >> 6));
    if (node >= N) return;
    float dd = dinv[node];
    float acc = dd * bf2f(xh[((size_t)node << 6) + lane]);  // self-loop
    int start = offs[node];
    int cnt = deg[node];
    const int* __restrict__ row = csr + start;
    int j = 0;
    for (; j + 16 <= cnt; j += 16) {
        int s[16];
        float w[16];
        ushort u[16];
#pragma unroll
        for (int q = 0; q < 16; ++q) s[q] = __builtin_amdgcn_readfirstlane(row[j + q]);
#pragma unroll
        for (int q = 0; q < 16; ++q) w[q] = dinv[s[q]];
#pragma unroll
        for (int q = 0; q < 16; ++q) u[q] = xh[((size_t)s[q] << 6) + lane];
#pragma unroll
        for (int q = 0; q < 16; ++q) acc += w[q] * bf2f(u[q]);
    }
    for (; j + 4 <= cnt; j += 4) {
        int s[4];
        float w[4];
        ushort u[4];
#pragma unroll
        for (int q = 0; q < 4; ++q) s[q] = __builtin_amdgcn_readfirstlane(row[j + q]);
#pragma unroll
        for (int q = 0; q < 4; ++q) w[q] = dinv[s[q]];
#pragma unroll
        for (int q = 0; q < 4; ++q) u[q] = xh[((size_t)s[q] << 6) + lane];
#pragma unroll
        for (int q = 0; q < 4; ++q) acc += w[q] * bf2f(u[q]);
    }
    for (; j < cnt; ++j) {
        int s = __builtin_amdgcn_readfirstlane(row[j]);
        acc += dinv[s] * bf2f(xh[((size_t)s << 6) + lane]);
    }
    out[((size_t)node << 6) + lane] = dd * acc;
}

// ---------------- LDS-tiled in-place matmul io = io @ W, fused stats ----------------
// Wl staged in LDS (R14's global-W variant was latency-bound: 25 -> 46us).
// k-loop rolled (#pragma unroll 1): full unroll spilled (VGPR=256, R4).
__global__ __launch_bounds__(THREADS) void matmul_stats_kernel(float* __restrict__ io,
                                                               const float* __restrict__ W,
                                                               float* __restrict__ stats, int N) {
    __shared__ float Wl[64 * 64];
    __shared__ float At[64 * AT_LD];
    __shared__ float bred[128];
    int tid = threadIdx.x;

    for (int i = tid; i < 1024; i += THREADS)
        ((float4*)Wl)[i] = ((const float4*)W)[i];

    int c0 = (tid & 15) * 4;
    int r0 = (tid >> 4) * 4;
    int ntiles = (N + 63) >> 6;
    float sums[4] = {0.f, 0.f, 0.f, 0.f};
    float sqs[4] = {0.f, 0.f, 0.f, 0.f};

    for (int tile = blockIdx.x; tile < ntiles; tile += gridDim.x) {
        int base = tile << 6;
        __syncthreads();
        for (int g = tid; g < 1024; g += THREADS) {
            int r = g >> 4, cc = (g & 15) << 2;
            int rowi = base + r;
            float4 v = {0.f, 0.f, 0.f, 0.f};
            if (rowi < N) v = *(const float4*)(io + ((size_t)rowi << 6) + cc);
            *(float4*)(&At[r * AT_LD + cc]) = v;
        }
        __syncthreads();

        float acc[4][4] = {};
#pragma unroll 1
        for (int k0 = 0; k0 < 64; k0 += 4) {
            float4 a[4], wf[4];
#pragma unroll
            for (int i = 0; i < 4; ++i)
                a[i] = *(const float4*)(&At[(r0 + i) * AT_LD + k0]);
#pragma unroll
            for (int q = 0; q < 4; ++q)
                wf[q] = *(const float4*)(&Wl[(k0 + q) * 64 + c0]);
#pragma unroll
            for (int i = 0; i < 4; ++i) {
                const float* ap = (const float*)&a[i];
#pragma unroll
                for (int j = 0; j < 4; ++j) {
                    acc[i][j] += ap[0] * ((const float*)&wf[0])[j] +
                                 ap[1] * ((const float*)&wf[1])[j] +
                                 ap[2] * ((const float*)&wf[2])[j] +
                                 ap[3] * ((const float*)&wf[3])[j];
                }
            }
        }

#pragma unroll
        for (int i = 0; i < 4; ++i) {
            int rowi = base + r0 + i;
            if (rowi < N) {
                float4 o = {acc[i][0], acc[i][1], acc[i][2], acc[i][3]};
                *(float4*)(io + ((size_t)rowi << 6) + c0) = o;
#pragma unroll
                for (int j = 0; j < 4; ++j) {
                    sums[j] += acc[i][j];
                    sqs[j] += acc[i][j] * acc[i][j];
                }
            }
        }
    }

    __syncthreads();
    if (tid < 128) bred[tid] = 0.f;
    __syncthreads();
#pragma unroll
    for (int j = 0; j < 4; ++j) {
        atomicAdd(&bred[c0 + j], sums[j]);
        atomicAdd(&bred[64 + c0 + j], sqs[j]);
    }
    __syncthreads();
    if (tid < 128) atomicAdd(&stats[tid], bred[tid]);
}

// ---------------- BN + ReLU in place ----------------
__global__ __launch_bounds__(THREADS) void bn_relu_kernel(float* __restrict__ io,
                                                          const float* __restrict__ stats,
                                                          const float* __restrict__ gamma,
                                                          const float* __restrict__ beta,
                                                          int n4, float invN) {
    int t = blockIdx.x * blockDim.x + threadIdx.x;
    if (t >= n4) return;
    int f0 = (t & 15) * 4;
    float4 v = ((const float4*)io)[t];
    float vv[4] = {v.x, v.y, v.z, v.w};
    float o[4];
#pragma unroll
    for (int j = 0; j < 4; ++j) {
        int f = f0 + j;
        float mean = stats[f] * invN;
        float var = stats[64 + f] * invN - mean * mean;
        float scale = gamma[f] * rsqrtf(var + BN_EPS);
        float shift = beta[f] - mean * scale;
        float y = vv[j] * scale + shift;
        o[j] = y > 0.f ? y : 0.f;
    }
    float4 r = {o[0], o[1], o[2], o[3]};
    ((float4*)io)[t] = r;
}

// ================= fallback (push path) kernels =================
__global__ __launch_bounds__(THREADS) void deg_kernel(const int* __restrict__ dst, int E,
                                                      int* __restrict__ deg) {
    int e = blockIdx.x * blockDim.x + threadIdx.x;
    if (e < E) atomicAdd(&deg[dst[e]], 1);
}

__global__ __launch_bounds__(THREADS) void dinv_kernel(const int* __restrict__ deg,
                                                       float* __restrict__ dinv, int N) {
    int i = blockIdx.x * blockDim.x + threadIdx.x;
    if (i < N) dinv[i] = rsqrtf((float)deg[i] + 1.0f);
}

__global__ __launch_bounds__(THREADS) void selfloop_kernel(const float4* __restrict__ x4,
                                                           const float* __restrict__ dinv,
                                                           float4* __restrict__ out4, int n4) {
    int t = blockIdx.x * blockDim.x + threadIdx.x;
    if (t >= n4) return;
    int node = t >> 4;
    float s = dinv[node];
    s *= s;
    float4 v = x4[t];
    v.x *= s; v.y *= s; v.z *= s; v.w *= s;
    out4[t] = v;
}

__global__ __launch_bounds__(THREADS) void scatter_kernel(const int* __restrict__ src,
                                                          const int* __restrict__ dst, int E,
                                                          const float* __restrict__ x,
                                                          const float* __restrict__ dinv,
                                                          float* __restrict__ out) {
    int lane = threadIdx.x & 63;
    int wave = (blockIdx.x * blockDim.x + threadIdx.x) >> 6;
    int nwaves = (gridDim.x * blockDim.x) >> 6;
    for (int e = wave; e < E; e += nwaves) {
        int s = src[e];
        int d = dst[e];
        float nrm = dinv[s] * dinv[d];
        atomicAdd(&out[d * 64 + lane], x[s * 64 + lane] * nrm);
    }
}

extern "C" void kernel_launch(void* const* d_in, const int* in_sizes, int n_in,
                              void* d_out, int out_size, void* d_ws, size_t ws_size,
                              hipStream_t stream) {
    const float* x     = (const float*)d_in[0];
    const int*   edges = (const int*)d_in[1];
    const float* W     = (const float*)d_in[2];
    // d_in[3] = b cancels exactly in training-mode BN
    const float* gamma = (const float*)d_in[4];
    const float* beta  = (const float*)d_in[5];
    float* out = (float*)d_out;

    const int N = in_sizes[0] / 64;
    const int E = in_sizes[1] / 2;
    const int* src = edges;
    const int* dst = edges + E;
    const int n4 = N * 16;

    const int nb = (N + 255) >> 8;                     // buckets
    const int avg = (E + nb - 1) / nb;
    const int cap = avg + (avg >> 2) + 512;            // ~8-sigma slack for Binomial load

    char* ws = (char*)d_ws;
    // layout: stats f32[128] | bcursor[256] | deg[N] | offs[N] | dinv[N] |
    //         csr[nb*cap] | staging[nb*cap] | xh[64N ushort]
    size_t off_stats   = 0;
    size_t off_bcursor = 512;
    size_t off_deg     = off_bcursor + 1024;
    size_t off_offs    = off_deg + (size_t)4 * N;
    size_t off_dinv    = off_offs + (size_t)4 * N;
    size_t off_csr     = off_dinv + (size_t)4 * N;
    size_t off_staging = off_csr + (size_t)4 * nb * cap;
    size_t off_xh      = (off_staging + (size_t)4 * nb * cap + 15) & ~(size_t)15;
    size_t need        = off_xh + (size_t)128 * N;

    if (ws_size >= need && N <= 65536) {
        float* stats   = (float*)(ws + off_stats);
        int*   bcursor = (int*)(ws + off_bcursor);
        int*   deg     = (int*)(ws + off_deg);
        int*   offs    = (int*)(ws + off_offs);
        float* dinv    = (float*)(ws + off_dinv);
        int*   csr     = (int*)(ws + off_csr);
        unsigned* staging = (unsigned*)(ws + off_staging);
        ushort* xh     = (ushort*)(ws + off_xh);

        int nseg = (E + SEG - 1) / SEG;
        int nPart = nseg < 1024 ? nseg : 1024;

        init_kernel<<<1, THREADS, 0, stream>>>(bcursor, cap, stats);
        conv_part_kernel<<<nPart + CONV_BLOCKS, THREADS, 0, stream>>>(
            src, dst, E, nPart, bcursor, staging, (const float4*)x, xh, n4);
        bucket_build_kernel<<<nb, THREADS, 0, stream>>>(staging, bcursor, cap, N, deg, offs,
                                                        dinv, csr);
        gather_bf16_kernel<<<(N * 64 + THREADS - 1) / THREADS, THREADS, 0, stream>>>(
            xh, offs, deg, csr, dinv, out, N);
        int ntiles = (N + 63) >> 6;
        matmul_stats_kernel<<<(ntiles < 1024 ? ntiles : 1024), THREADS, 0, stream>>>(
            out, W, stats, N);
        bn_relu_kernel<<<(n4 + THREADS - 1) / THREADS, THREADS, 0, stream>>>(
            out, stats, gamma, beta, n4, 1.0f / (float)N);
    } else {
        // fallback: push path (ws: deg[N] | stats[128] | dinv[N])
        int*   deg   = (int*)ws;
        float* stats = (float*)(ws + (size_t)N * 4);
        float* dinv  = (float*)(ws + (size_t)N * 4 + 512);

        hipMemsetAsync(ws, 0, (size_t)N * 4 + 512, stream);
        deg_kernel<<<(E + THREADS - 1) / THREADS, THREADS, 0, stream>>>(dst, E, deg);
        dinv_kernel<<<(N + THREADS - 1) / THREADS, THREADS, 0, stream>>>(deg, dinv, N);
        selfloop_kernel<<<(n4 + THREADS - 1) / THREADS, THREADS, 0, stream>>>(
            (const float4*)x, dinv, (float4*)out, n4);
        scatter_kernel<<<1024, THREADS, 0, stream>>>(src, dst, E, x, dinv, out);
        matmul_stats_kernel<<<512, THREADS, 0, stream>>>(out, W, stats, N);
        bn_relu_kernel<<<(n4 + THREADS - 1) / THREADS, THREADS, 0, stream>>>(
            out, stats, gamma, beta, n4, 1.0f / (float)N);
    }
}